// Round 1
// baseline (659.833 us; speedup 1.0000x reference)
//
#include <hip/hip_runtime.h>

#define RS2 0.70710678118654752f

// CRZ ring sign table: s(b) = sum_i c_i*(2*c_{(i+1)%4}-1), c_i = bit (3-i) of b
__device__ __constant__ const int kCrz[16] = {0,-1,-1,0,-1,-2,0,1,-1,0,-2,1,0,1,1,4};

struct U2 { float r00,i00,r01,i01,r10,i10,r11,i11; };

// U = RZ(a) * U : row0 *= (c - i s), row1 *= (c + i s), with c=cos(a/2), s=sin(a/2)
__device__ __forceinline__ void u_rz(U2& u, float a) {
  float s, c;
  __sincosf(0.5f * a, &s, &c);
  float t;
  t = u.r00; u.r00 = c*t + s*u.i00; u.i00 = c*u.i00 - s*t;
  t = u.r01; u.r01 = c*t + s*u.i01; u.i01 = c*u.i01 - s*t;
  t = u.r10; u.r10 = c*t - s*u.i10; u.i10 = c*u.i10 + s*t;
  t = u.r11; u.r11 = c*t - s*u.i11; u.i11 = c*u.i11 + s*t;
}

// U = RY(a) * U : row0' = c*row0 - s*row1 ; row1' = s*row0 + c*row1
__device__ __forceinline__ void u_ry(U2& u, float a) {
  float s, c;
  __sincosf(0.5f * a, &s, &c);
  float t0r,t0i,t1r,t1i;
  t0r=u.r00; t0i=u.i00; t1r=u.r10; t1i=u.i10;
  u.r00 = c*t0r - s*t1r; u.i00 = c*t0i - s*t1i;
  u.r10 = s*t0r + c*t1r; u.i10 = s*t0i + c*t1i;
  t0r=u.r01; t0i=u.i01; t1r=u.r11; t1i=u.i11;
  u.r01 = c*t0r - s*t1r; u.i01 = c*t0i - s*t1i;
  u.r11 = s*t0r + c*t1r; u.i11 = s*t0i + c*t1i;
}

// apply 2x2 complex U on wire with stride R = 2^(3-w)
template<int R>
__device__ __forceinline__ void apply1q(float* sr, float* si, const U2& u) {
#pragma unroll
  for (int base = 0; base < 16; base += 2*R) {
#pragma unroll
    for (int k = 0; k < R; ++k) {
      const int n0 = base + k, n1 = n0 + R;
      float ar = sr[n0], ai = si[n0];
      float br = sr[n1], bi = si[n1];
      sr[n0] = u.r00*ar - u.i00*ai + u.r01*br - u.i01*bi;
      si[n0] = u.r00*ai + u.i00*ar + u.r01*bi + u.i01*br;
      sr[n1] = u.r10*ar - u.i10*ai + u.r11*br - u.i11*bi;
      si[n1] = u.r10*ai + u.i10*ar + u.r11*bi + u.i11*br;
    }
  }
}

// apply real rotation [[c,-s],[s,c]] on wire with stride R
template<int R>
__device__ __forceinline__ void apply_ry_real(float* sr, float* si, float c, float s) {
#pragma unroll
  for (int base = 0; base < 16; base += 2*R) {
#pragma unroll
    for (int k = 0; k < R; ++k) {
      const int n0 = base + k, n1 = n0 + R;
      float ar = sr[n0], ai = si[n0];
      float br = sr[n1], bi = si[n1];
      sr[n0] = c*ar - s*br;  si[n0] = c*ai - s*bi;
      sr[n1] = s*ar + c*br;  si[n1] = s*ai + c*bi;
    }
  }
}

__global__ void __launch_bounds__(64)
quanv_kernel(const float* __restrict__ x,
             const float* __restrict__ crz_t,
             const float* __restrict__ ry_t,
             const float* __restrict__ fc1_w,
             const float* __restrict__ fc1_b,
             const float* __restrict__ fc2_w,
             const float* __restrict__ fc2_b,
             float* __restrict__ out, int B)
{
  __shared__ float sw[20 * 784];
  const int tid = threadIdx.x;
  // stage fc1_w into LDS (coalesced float4)
  for (int i = tid; i < (20 * 784) / 4; i += 64)
    ((float4*)sw)[i] = ((const float4*)fc1_w)[i];
  __syncthreads();

  const int b = blockIdx.x * 64 + tid;
  if (b >= B) return;
  const float* img = x + (size_t)b * 784;

  // scalar-derived constants (uniform across threads)
  const float theta = crz_t[0];
  const float ryt   = ry_t[0];
  float c1,s1,c2,s2,c4,s4,cry,sry;
  __sincosf(0.5f*theta, &s1, &c1);
  __sincosf(theta,      &s2, &c2);
  __sincosf(2.0f*theta, &s4, &c4);
  __sincosf(0.5f*ryt,   &sry, &cry);

  float sr[16], si[16];
#pragma unroll
  for (int n = 0; n < 16; ++n) { sr[n] = 0.f; si[n] = 0.f; }
  sr[0] = 1.f;

  float h1[20];
#pragma unroll
  for (int j = 0; j < 20; ++j) h1[j] = 0.f;

  for (int wi = 0; wi < 14; ++wi) {
    const int r0 = 2 * wi;
    const int h = (wi == 13) ? 2 : 4;       // valid rows in window
    float P[4][4];
    // j=0: load cols 0..3 for 4 rows (float4, 28 is divisible by 4 -> aligned)
#pragma unroll
    for (int r = 0; r < 4; ++r) {
      if (r < h) {
        float4 v = *(const float4*)(img + (r0 + r) * 28);
        P[r][0]=v.x; P[r][1]=v.y; P[r][2]=v.z; P[r][3]=v.w;
      } else {
        P[r][0]=0.f; P[r][1]=0.f; P[r][2]=0.f; P[r][3]=0.f;
      }
    }

    for (int wj = 0; wj < 14; ++wj) {
      if (wj > 0) {
        // slide window right by 2: reuse right half, load 2 new cols
#pragma unroll
        for (int r = 0; r < 4; ++r) { P[r][0] = P[r][2]; P[r][1] = P[r][3]; }
        const int c0 = 2 * wj + 2;
        if (c0 < 28) {
#pragma unroll
          for (int r = 0; r < 4; ++r) {
            if (r < h) {
              float2 v = *(const float2*)(img + (r0 + r) * 28 + c0);
              P[r][2] = v.x; P[r][3] = v.y;
            } else { P[r][2] = 0.f; P[r][3] = 0.f; }
          }
        } else {
#pragma unroll
          for (int r = 0; r < 4; ++r) { P[r][2] = 0.f; P[r][3] = 0.f; }
        }
      }
      const int w = (wj == 13) ? 2 : 4;     // valid cols in window

      // pack window values in reference order: r in [0,h), c in [0,w), then zeros
      float f[16];
      if (h == 4 && w == 4) {
#pragma unroll
        for (int k = 0; k < 16; ++k) f[k] = P[k >> 2][k & 3];
      } else if (h == 4) {                   // w == 2
#pragma unroll
        for (int r = 0; r < 4; ++r) { f[2*r] = P[r][0]; f[2*r+1] = P[r][1]; }
#pragma unroll
        for (int k = 8; k < 16; ++k) f[k] = 0.f;
      } else if (w == 4) {                   // h == 2
#pragma unroll
        for (int k = 0; k < 8; ++k) f[k] = P[k >> 2][k & 3];
#pragma unroll
        for (int k = 8; k < 16; ++k) f[k] = 0.f;
      } else {                               // h == 2, w == 2
        f[0]=P[0][0]; f[1]=P[0][1]; f[2]=P[1][0]; f[3]=P[1][1];
#pragma unroll
        for (int k = 4; k < 16; ++k) f[k] = 0.f;
      }

      // ---- quantum circuit step ----
      U2 u;
      // wire 0: U = RZ(f4) RY(f3) RZ(f2) RY(f1) RZ(f0) H , stride 8
      u = {RS2,0.f, RS2,0.f, RS2,0.f, -RS2,0.f};
      u_rz(u, f[0]); u_ry(u, f[1]); u_rz(u, f[2]); u_ry(u, f[3]); u_rz(u, f[4]);
      apply1q<8>(sr, si, u);
      // wire 1, stride 4
      u = {RS2,0.f, RS2,0.f, RS2,0.f, -RS2,0.f};
      u_rz(u, f[5]); u_ry(u, f[6]); u_rz(u, f[7]); u_ry(u, f[8]); u_rz(u, f[9]);
      apply1q<4>(sr, si, u);
      // wire 2, stride 2
      u = {RS2,0.f, RS2,0.f, RS2,0.f, -RS2,0.f};
      u_rz(u, f[10]); u_ry(u, f[11]); u_rz(u, f[12]); u_ry(u, f[13]); u_rz(u, f[14]);
      apply1q<2>(sr, si, u);
      // wire 3: U = RZ(f15) H , stride 1
      u = {RS2,0.f, RS2,0.f, RS2,0.f, -RS2,0.f};
      u_rz(u, f[15]);
      apply1q<1>(sr, si, u);

      // CRZ ring diagonal: state[n] *= exp(0.5i * theta * kCrz[n])
#pragma unroll
      for (int n = 0; n < 16; ++n) {
        const int sg = kCrz[n];
        if (sg == 0) continue;
        float cc, ss;
        if      (sg ==  1) { cc = c1; ss =  s1; }
        else if (sg == -1) { cc = c1; ss = -s1; }
        else if (sg ==  2) { cc = c2; ss =  s2; }
        else if (sg == -2) { cc = c2; ss = -s2; }
        else               { cc = c4; ss =  s4; }  // sg == 4
        float r = sr[n], im = si[n];
        sr[n] = cc*r - ss*im;
        si[n] = cc*im + ss*r;
      }

      // Ry(ry_theta) on all 4 wires
      apply_ry_real<8>(sr, si, cry, sry);
      apply_ry_real<4>(sr, si, cry, sry);
      apply_ry_real<2>(sr, si, cry, sry);
      apply_ry_real<1>(sr, si, cry, sry);

      // Z expectations: o_i = sum_n |s_n|^2 * (1 - 2*bit(3-i) of n)
      float o0 = 0.f, o1 = 0.f, o2 = 0.f, o3 = 0.f;
#pragma unroll
      for (int n = 0; n < 16; ++n) {
        float p = sr[n]*sr[n] + si[n]*si[n];
        o0 += (n & 8) ? -p : p;
        o1 += (n & 4) ? -p : p;
        o2 += (n & 2) ? -p : p;
        o3 += (n & 1) ? -p : p;
      }

      // fold into fc1: h1[j] += W[j, win*4 + i] * o_i
      const int win4 = (wi * 14 + wj) * 4;
#pragma unroll
      for (int j = 0; j < 20; ++j) {
        float4 wv = *(const float4*)&sw[j * 784 + win4];
        h1[j] = fmaf(wv.x, o0, fmaf(wv.y, o1, fmaf(wv.z, o2, fmaf(wv.w, o3, h1[j]))));
      }
    }
  }

  // epilogue: bias, leaky relu, fc2
  float acc0 = fc2_b[0], acc1 = fc2_b[1];
#pragma unroll
  for (int j = 0; j < 20; ++j) {
    float v = h1[j] + fc1_b[j];
    v = (v > 0.f) ? v : 0.1f * v;
    acc0 = fmaf(fc2_w[j],      v, acc0);
    acc1 = fmaf(fc2_w[20 + j], v, acc1);
  }
  float2 res; res.x = acc0; res.y = acc1;
  *(float2*)(out + (size_t)b * 2) = res;
}

extern "C" void kernel_launch(void* const* d_in, const int* in_sizes, int n_in,
                              void* d_out, int out_size, void* d_ws, size_t ws_size,
                              hipStream_t stream) {
  const float* x      = (const float*)d_in[0];
  const float* crz_t  = (const float*)d_in[1];
  const float* ry_t   = (const float*)d_in[2];
  const float* fc1_w  = (const float*)d_in[3];
  const float* fc1_b  = (const float*)d_in[4];
  const float* fc2_w  = (const float*)d_in[5];
  const float* fc2_b  = (const float*)d_in[6];
  float* out = (float*)d_out;
  const int B = in_sizes[0] / 784;
  const int grid = (B + 63) / 64;
  quanv_kernel<<<grid, 64, 0, stream>>>(x, crz_t, ry_t, fc1_w, fc1_b,
                                        fc2_w, fc2_b, out, B);
}

// Round 2
// 329.257 us; speedup vs baseline: 2.0040x; 2.0040x over previous
//
#include <hip/hip_runtime.h>

#define RS2 0.70710678118654752f

// ds_swizzle immediates (BitMode: offset = (xor<<10)|(or<<5)|and)
#define SWZ_XOR1 0x041F   // partner = lane ^ 1
#define SWZ_XOR2 0x081F   // partner = lane ^ 2
#define SWZ_BC0  0x001C   // broadcast from in-group lane 0  (src = (i&0x1C)|w)
#define SWZ_BC1  0x003C
#define SWZ_BC2  0x005C
#define SWZ_BC3  0x007C

template<int IMM> __device__ __forceinline__ float swzf(float x) {
  return __int_as_float(__builtin_amdgcn_ds_swizzle(__float_as_int(x), IMM));
}

struct U2 { float r00,i00,r01,i01,r10,i10,r11,i11; };

// U = RZ(a) * U : row0 *= (c - i s), row1 *= (c + i s), c=cos(a/2), s=sin(a/2)
__device__ __forceinline__ void u_rz(U2& u, float a) {
  float s, c;
  __sincosf(0.5f * a, &s, &c);
  float t;
  t = u.r00; u.r00 = c*t + s*u.i00; u.i00 = c*u.i00 - s*t;
  t = u.r01; u.r01 = c*t + s*u.i01; u.i01 = c*u.i01 - s*t;
  t = u.r10; u.r10 = c*t - s*u.i10; u.i10 = c*u.i10 + s*t;
  t = u.r11; u.r11 = c*t - s*u.i11; u.i11 = c*u.i11 + s*t;
}

// U = RY(a) * U : row0' = c*row0 - s*row1 ; row1' = s*row0 + c*row1
__device__ __forceinline__ void u_ry(U2& u, float a) {
  float s, c;
  __sincosf(0.5f * a, &s, &c);
  float t0r,t0i,t1r,t1i;
  t0r=u.r00; t0i=u.i00; t1r=u.r10; t1i=u.i10;
  u.r00 = c*t0r - s*t1r; u.i00 = c*t0i - s*t1i;
  u.r10 = s*t0r + c*t1r; u.i10 = s*t0i + c*t1i;
  t0r=u.r01; t0i=u.i01; t1r=u.r11; t1i=u.i11;
  u.r01 = c*t0r - s*t1r; u.i01 = c*t0i - s*t1i;
  u.r11 = s*t0r + c*t1r; u.i11 = s*t0i + c*t1i;
}

__global__ void __launch_bounds__(256)
quanv_kernel(const float* __restrict__ x,
             const float* __restrict__ crz_t,
             const float* __restrict__ ry_t,
             const float* __restrict__ fc1_w,
             const float* __restrict__ fc1_b,
             const float* __restrict__ fc2_w,
             const float* __restrict__ fc2_b,
             float* __restrict__ out, int B)
{
  __shared__ float sw[20 * 784];
  const int tid = threadIdx.x;
  for (int i = tid; i < (20 * 784) / 4; i += 256)
    ((float4*)sw)[i] = ((const float4*)fc1_w)[i];
  __syncthreads();

  const int l = tid & 3;                       // lane within 4-lane group
  const int b = (blockIdx.x * 256 + tid) >> 2; // element id
  if (b >= B) return;                          // whole group exits together
  const float* img = x + (size_t)b * 784;

  // ---- uniform scalar-derived constants ----
  const float theta = crz_t[0];
  const float ryt   = ry_t[0];
  float cry, sry;
  __sincosf(0.5f * ryt, &sry, &cry);
  // Ry partner-term sign per lane (row0: -s*partner, row1: +s*partner)
  const float sgn0 = (l & 2) ? sry : -sry;   // wire 0 (bit = l>>1)
  const float sgn1 = (l & 1) ? sry : -sry;   // wire 1 (bit = l&1)

  // CRZ ring diag exp(0.5i*theta*sg[n]) for this lane's 4 amps (n = 4l+k)
  float g0,g1,g2,g3;
  if      (l == 0) { g0= 0.f; g1=-1.f; g2=-1.f; g3=0.f; }
  else if (l == 1) { g0=-1.f; g1=-2.f; g2= 0.f; g3=1.f; }
  else if (l == 2) { g0=-1.f; g1= 0.f; g2=-2.f; g3=1.f; }
  else             { g0= 0.f; g1= 1.f; g2= 1.f; g3=4.f; }
  float czk[4], szk[4];
  __sincosf(0.5f*theta*g0, &szk[0], &czk[0]);
  __sincosf(0.5f*theta*g1, &szk[1], &czk[1]);
  __sincosf(0.5f*theta*g2, &szk[2], &czk[2]);
  __sincosf(0.5f*theta*g3, &szk[3], &czk[3]);

  // state: amp n = 4*l + k  (bits: b0=l>>1, b1=l&1, b2=k>>1, b3=k&1)
  float sr[4], si[4];
#pragma unroll
  for (int k = 0; k < 4; ++k) { sr[k] = 0.f; si[k] = 0.f; }
  if (l == 0) sr[0] = 1.f;

  float h1[5];                                 // fc1 rows 5l..5l+4
#pragma unroll
  for (int j = 0; j < 5; ++j) h1[j] = 0.f;
  const float* swl = sw + 5 * l * 784;

  for (int wi = 0; wi < 14; ++wi) {
    const int r0 = 2 * wi;
    const bool hFull = (wi != 13);             // valid rows: 4 or 2
    float P[4][4];
#pragma unroll
    for (int r = 0; r < 4; ++r) {
      if (r < (hFull ? 4 : 2)) {
        float4 v = *(const float4*)(img + (r0 + r) * 28);
        P[r][0]=v.x; P[r][1]=v.y; P[r][2]=v.z; P[r][3]=v.w;
      } else {
        P[r][0]=0.f; P[r][1]=0.f; P[r][2]=0.f; P[r][3]=0.f;
      }
    }

    for (int wj = 0; wj < 14; ++wj) {
      if (wj > 0) {
#pragma unroll
        for (int r = 0; r < 4; ++r) { P[r][0] = P[r][2]; P[r][1] = P[r][3]; }
        const int c0 = 2 * wj + 2;
        if (c0 < 28) {
#pragma unroll
          for (int r = 0; r < 4; ++r) {
            if (r < (hFull ? 4 : 2)) {
              float2 v = *(const float2*)(img + (r0 + r) * 28 + c0);
              P[r][2] = v.x; P[r][3] = v.y;
            } else { P[r][2] = 0.f; P[r][3] = 0.f; }
          }
        } else {
#pragma unroll
          for (int r = 0; r < 4; ++r) { P[r][2] = 0.f; P[r][3] = 0.f; }
        }
      }
      const bool wFull = (wj != 13);

      // ---- per-lane angle pick: lane l gets packed f[5l .. 5l+4] ----
      float a0=0.f, a1=0.f, a2=0.f, a3=0.f, a4=0.f;
      if (hFull && wFull) {                    // f[k] = P[k>>2][k&3]
        if      (l == 0) { a0=P[0][0]; a1=P[0][1]; a2=P[0][2]; a3=P[0][3]; a4=P[1][0]; }
        else if (l == 1) { a0=P[1][1]; a1=P[1][2]; a2=P[1][3]; a3=P[2][0]; a4=P[2][1]; }
        else if (l == 2) { a0=P[2][2]; a1=P[2][3]; a2=P[3][0]; a3=P[3][1]; a4=P[3][2]; }
        else             { a0=P[3][3]; }
      } else if (hFull) {                      // w=2: f = P00,P01,P10,P11,P20,P21,P30,P31
        if      (l == 0) { a0=P[0][0]; a1=P[0][1]; a2=P[1][0]; a3=P[1][1]; a4=P[2][0]; }
        else if (l == 1) { a0=P[2][1]; a1=P[3][0]; a2=P[3][1]; }
      } else if (wFull) {                      // h=2: f = P00..P03,P10..P13
        if      (l == 0) { a0=P[0][0]; a1=P[0][1]; a2=P[0][2]; a3=P[0][3]; a4=P[1][0]; }
        else if (l == 1) { a0=P[1][1]; a1=P[1][2]; a2=P[1][3]; }
      } else {                                 // h=2,w=2: f = P00,P01,P10,P11
        if      (l == 0) { a0=P[0][0]; a1=P[0][1]; a2=P[1][0]; a3=P[1][1]; }
      }

      // ---- lane l builds U for wire l: RZ(a4)RY(a3)RZ(a2)RY(a1)RZ(a0)·H ----
      U2 u = {RS2,0.f, RS2,0.f, RS2,0.f, -RS2,0.f};
      u_rz(u, a0); u_ry(u, a1); u_rz(u, a2); u_ry(u, a3); u_rz(u, a4);

      // ---- wire 0 (partner lane^2, row bit = l>>1) ----
      {
        float b00r=swzf<SWZ_BC0>(u.r00), b00i=swzf<SWZ_BC0>(u.i00);
        float b01r=swzf<SWZ_BC0>(u.r01), b01i=swzf<SWZ_BC0>(u.i01);
        float b10r=swzf<SWZ_BC0>(u.r10), b10i=swzf<SWZ_BC0>(u.i10);
        float b11r=swzf<SWZ_BC0>(u.r11), b11i=swzf<SWZ_BC0>(u.i11);
        const bool hi = (l & 2);
        float uar = hi ? b11r : b00r, uai = hi ? b11i : b00i;
        float ubr = hi ? b10r : b01r, ubi = hi ? b10i : b01i;
#pragma unroll
        for (int k = 0; k < 4; ++k) {
          float pr = swzf<SWZ_XOR2>(sr[k]), pi = swzf<SWZ_XOR2>(si[k]);
          float ar = sr[k], ai = si[k];
          sr[k] = uar*ar - uai*ai + ubr*pr - ubi*pi;
          si[k] = uar*ai + uai*ar + ubr*pi + ubi*pr;
        }
      }
      // ---- wire 1 (partner lane^1, row bit = l&1) ----
      {
        float b00r=swzf<SWZ_BC1>(u.r00), b00i=swzf<SWZ_BC1>(u.i00);
        float b01r=swzf<SWZ_BC1>(u.r01), b01i=swzf<SWZ_BC1>(u.i01);
        float b10r=swzf<SWZ_BC1>(u.r10), b10i=swzf<SWZ_BC1>(u.i10);
        float b11r=swzf<SWZ_BC1>(u.r11), b11i=swzf<SWZ_BC1>(u.i11);
        const bool hi = (l & 1);
        float uar = hi ? b11r : b00r, uai = hi ? b11i : b00i;
        float ubr = hi ? b10r : b01r, ubi = hi ? b10i : b01i;
#pragma unroll
        for (int k = 0; k < 4; ++k) {
          float pr = swzf<SWZ_XOR1>(sr[k]), pi = swzf<SWZ_XOR1>(si[k]);
          float ar = sr[k], ai = si[k];
          sr[k] = uar*ar - uai*ai + ubr*pr - ubi*pi;
          si[k] = uar*ai + uai*ar + ubr*pi + ubi*pr;
        }
      }
      // ---- wire 2 (local pairs (k, k+2)) ----
      {
        float c00r=swzf<SWZ_BC2>(u.r00), c00i=swzf<SWZ_BC2>(u.i00);
        float c01r=swzf<SWZ_BC2>(u.r01), c01i=swzf<SWZ_BC2>(u.i01);
        float c10r=swzf<SWZ_BC2>(u.r10), c10i=swzf<SWZ_BC2>(u.i10);
        float c11r=swzf<SWZ_BC2>(u.r11), c11i=swzf<SWZ_BC2>(u.i11);
#pragma unroll
        for (int k = 0; k < 2; ++k) {
          float ar=sr[k], ai=si[k], br=sr[k+2], bi=si[k+2];
          sr[k]   = c00r*ar - c00i*ai + c01r*br - c01i*bi;
          si[k]   = c00r*ai + c00i*ar + c01r*bi + c01i*br;
          sr[k+2] = c10r*ar - c10i*ai + c11r*br - c11i*bi;
          si[k+2] = c10r*ai + c10i*ar + c11r*bi + c11i*br;
        }
      }
      // ---- wire 3 (local pairs (k, k+1)) ----
      {
        float c00r=swzf<SWZ_BC3>(u.r00), c00i=swzf<SWZ_BC3>(u.i00);
        float c01r=swzf<SWZ_BC3>(u.r01), c01i=swzf<SWZ_BC3>(u.i01);
        float c10r=swzf<SWZ_BC3>(u.r10), c10i=swzf<SWZ_BC3>(u.i10);
        float c11r=swzf<SWZ_BC3>(u.r11), c11i=swzf<SWZ_BC3>(u.i11);
#pragma unroll
        for (int k = 0; k < 4; k += 2) {
          float ar=sr[k], ai=si[k], br=sr[k+1], bi=si[k+1];
          sr[k]   = c00r*ar - c00i*ai + c01r*br - c01i*bi;
          si[k]   = c00r*ai + c00i*ar + c01r*bi + c01i*br;
          sr[k+1] = c10r*ar - c10i*ai + c11r*br - c11i*bi;
          si[k+1] = c10r*ai + c10i*ar + c11r*bi + c11i*br;
        }
      }

      // ---- CRZ ring diagonal (per-lane precomputed) ----
#pragma unroll
      for (int k = 0; k < 4; ++k) {
        float r = sr[k], im = si[k];
        sr[k] = czk[k]*r - szk[k]*im;
        si[k] = czk[k]*im + szk[k]*r;
      }

      // ---- Ry(ryt) on wires 0,1 (cross-lane) ----
#pragma unroll
      for (int k = 0; k < 4; ++k) {
        float pr = swzf<SWZ_XOR2>(sr[k]), pi = swzf<SWZ_XOR2>(si[k]);
        sr[k] = cry*sr[k] + sgn0*pr;
        si[k] = cry*si[k] + sgn0*pi;
      }
#pragma unroll
      for (int k = 0; k < 4; ++k) {
        float pr = swzf<SWZ_XOR1>(sr[k]), pi = swzf<SWZ_XOR1>(si[k]);
        sr[k] = cry*sr[k] + sgn1*pr;
        si[k] = cry*si[k] + sgn1*pi;
      }
      // ---- Ry on wires 2,3 (local) ----
#pragma unroll
      for (int k = 0; k < 2; ++k) {
        float ar=sr[k], br=sr[k+2];  sr[k]=cry*ar - sry*br;  sr[k+2]=sry*ar + cry*br;
        float ai=si[k], bi=si[k+2];  si[k]=cry*ai - sry*bi;  si[k+2]=sry*ai + cry*bi;
      }
#pragma unroll
      for (int k = 0; k < 4; k += 2) {
        float ar=sr[k], br=sr[k+1];  sr[k]=cry*ar - sry*br;  sr[k+1]=sry*ar + cry*br;
        float ai=si[k], bi=si[k+1];  si[k]=cry*ai - sry*bi;  si[k+1]=sry*ai + cry*bi;
      }

      // ---- Z expectations: per-lane partials then 4-lane butterfly ----
      float p0 = sr[0]*sr[0] + si[0]*si[0];
      float p1 = sr[1]*sr[1] + si[1]*si[1];
      float p2 = sr[2]*sr[2] + si[2]*si[2];
      float p3 = sr[3]*sr[3] + si[3]*si[3];
      float s01 = p0 + p1, s23 = p2 + p3;
      float t   = s01 + s23;
      float o0 = (l & 2) ? -t : t;          // sign = bit b0 = l>>1
      float o1 = (l & 1) ? -t : t;          // sign = bit b1 = l&1
      float o2 = s01 - s23;                 // sign = bit b2 = k>>1
      float o3 = (p0 - p1) + (p2 - p3);     // sign = bit b3 = k&1
      o0 += swzf<SWZ_XOR1>(o0); o0 += swzf<SWZ_XOR2>(o0);
      o1 += swzf<SWZ_XOR1>(o1); o1 += swzf<SWZ_XOR2>(o1);
      o2 += swzf<SWZ_XOR1>(o2); o2 += swzf<SWZ_XOR2>(o2);
      o3 += swzf<SWZ_XOR1>(o3); o3 += swzf<SWZ_XOR2>(o3);

      // ---- fc1 partial: this lane's 5 rows ----
      const int win4 = (wi * 14 + wj) * 4;
#pragma unroll
      for (int j = 0; j < 5; ++j) {
        float4 wv = *(const float4*)(swl + j * 784 + win4);
        h1[j] = fmaf(wv.x, o0, fmaf(wv.y, o1, fmaf(wv.z, o2, fmaf(wv.w, o3, h1[j]))));
      }
    }
  }

  // ---- epilogue: bias + leaky relu + fc2, reduce over group ----
  float pa = 0.f, pb = 0.f;
#pragma unroll
  for (int j = 0; j < 5; ++j) {
    const int r = 5 * l + j;
    float v = h1[j] + fc1_b[r];
    v = (v > 0.f) ? v : 0.1f * v;
    pa = fmaf(fc2_w[r],      v, pa);
    pb = fmaf(fc2_w[20 + r], v, pb);
  }
  pa += swzf<SWZ_XOR1>(pa); pa += swzf<SWZ_XOR2>(pa);
  pb += swzf<SWZ_XOR1>(pb); pb += swzf<SWZ_XOR2>(pb);
  if (l == 0) {
    float2 res; res.x = pa + fc2_b[0]; res.y = pb + fc2_b[1];
    *(float2*)(out + (size_t)b * 2) = res;
  }
}

extern "C" void kernel_launch(void* const* d_in, const int* in_sizes, int n_in,
                              void* d_out, int out_size, void* d_ws, size_t ws_size,
                              hipStream_t stream) {
  const float* x      = (const float*)d_in[0];
  const float* crz_t  = (const float*)d_in[1];
  const float* ry_t   = (const float*)d_in[2];
  const float* fc1_w  = (const float*)d_in[3];
  const float* fc1_b  = (const float*)d_in[4];
  const float* fc2_w  = (const float*)d_in[5];
  const float* fc2_b  = (const float*)d_in[6];
  float* out = (float*)d_out;
  const int B = in_sizes[0] / 784;
  const int grid = (B * 4 + 255) / 256;
  quanv_kernel<<<grid, 256, 0, stream>>>(x, crz_t, ry_t, fc1_w, fc1_b,
                                         fc2_w, fc2_b, out, B);
}

// Round 3
// 287.602 us; speedup vs baseline: 2.2943x; 1.1448x over previous
//
#include <hip/hip_runtime.h>

#define RS2 0.70710678118654752f

// DPP quad_perm encodings: sel0 | sel1<<2 | sel2<<4 | sel3<<6
#define QP_XOR1 0xB1   // [1,0,3,2]
#define QP_XOR2 0x4E   // [2,3,0,1]
#define QP_BC0  0x00   // [0,0,0,0]
#define QP_BC1  0x55   // [1,1,1,1]
#define QP_BC2  0xAA   // [2,2,2,2]
#define QP_BC3  0xFF   // [3,3,3,3]

template<int CTRL> __device__ __forceinline__ float dppf(float x) {
  return __int_as_float(__builtin_amdgcn_update_dpp(
      0, __float_as_int(x), CTRL, 0xF, 0xF, true));
}

struct U2 { float r00,i00,r01,i01,r10,i10,r11,i11; };

// U = RZ(a) * U : row0 *= (c - i s), row1 *= (c + i s), c=cos(a/2), s=sin(a/2)
__device__ __forceinline__ void u_rz(U2& u, float a) {
  float s, c;
  __sincosf(0.5f * a, &s, &c);
  float t;
  t = u.r00; u.r00 = c*t + s*u.i00; u.i00 = c*u.i00 - s*t;
  t = u.r01; u.r01 = c*t + s*u.i01; u.i01 = c*u.i01 - s*t;
  t = u.r10; u.r10 = c*t - s*u.i10; u.i10 = c*u.i10 + s*t;
  t = u.r11; u.r11 = c*t - s*u.i11; u.i11 = c*u.i11 + s*t;
}

// U = RY(a) * U : row0' = c*row0 - s*row1 ; row1' = s*row0 + c*row1
__device__ __forceinline__ void u_ry(U2& u, float a) {
  float s, c;
  __sincosf(0.5f * a, &s, &c);
  float t0r,t0i,t1r,t1i;
  t0r=u.r00; t0i=u.i00; t1r=u.r10; t1i=u.i10;
  u.r00 = c*t0r - s*t1r; u.i00 = c*t0i - s*t1i;
  u.r10 = s*t0r + c*t1r; u.i10 = s*t0i + c*t1i;
  t0r=u.r01; t0i=u.i01; t1r=u.r11; t1i=u.i11;
  u.r01 = c*t0r - s*t1r; u.i01 = c*t0i - s*t1i;
  u.r11 = s*t0r + c*t1r; u.i11 = s*t0i + c*t1i;
}

__global__ void __launch_bounds__(256)
quanv_kernel(const float* __restrict__ x,
             const float* __restrict__ crz_t,
             const float* __restrict__ ry_t,
             const float* __restrict__ fc1_w,
             const float* __restrict__ fc1_b,
             const float* __restrict__ fc2_w,
             const float* __restrict__ fc2_b,
             float* __restrict__ out, int B)
{
  __shared__ float sw[20 * 784];
  const int tid = threadIdx.x;
  for (int i = tid; i < (20 * 784) / 4; i += 256)
    ((float4*)sw)[i] = ((const float4*)fc1_w)[i];
  __syncthreads();

  const int l = tid & 3;                       // lane within 4-lane group
  const int b = (blockIdx.x * 256 + tid) >> 2; // element id
  if (b >= B) return;                          // whole group exits together
  const float* img = x + (size_t)b * 784;

  // ---- uniform scalar-derived constants ----
  const float theta = crz_t[0];
  const float ryt   = ry_t[0];
  float cry, sry;
  __sincosf(0.5f * ryt, &sry, &cry);
  // Ry partner-term sign per lane (row0: -s*partner, row1: +s*partner)
  const float sgn0 = (l & 2) ? sry : -sry;   // wire 0 (bit = l>>1)
  const float sgn1 = (l & 1) ? sry : -sry;   // wire 1 (bit = l&1)

  // CRZ ring diag exp(0.5i*theta*sg[n]) for this lane's 4 amps (n = 4l+k)
  float g0,g1,g2,g3;
  if      (l == 0) { g0= 0.f; g1=-1.f; g2=-1.f; g3=0.f; }
  else if (l == 1) { g0=-1.f; g1=-2.f; g2= 0.f; g3=1.f; }
  else if (l == 2) { g0=-1.f; g1= 0.f; g2=-2.f; g3=1.f; }
  else             { g0= 0.f; g1= 1.f; g2= 1.f; g3=4.f; }
  float czk[4], szk[4];
  __sincosf(0.5f*theta*g0, &szk[0], &czk[0]);
  __sincosf(0.5f*theta*g1, &szk[1], &czk[1]);
  __sincosf(0.5f*theta*g2, &szk[2], &czk[2]);
  __sincosf(0.5f*theta*g3, &szk[3], &czk[3]);

  // state: amp n = 4*l + k  (bits: b0=l>>1, b1=l&1, b2=k>>1, b3=k&1)
  float sr[4], si[4];
#pragma unroll
  for (int k = 0; k < 4; ++k) { sr[k] = 0.f; si[k] = 0.f; }
  if (l == 0) sr[0] = 1.f;

  float h1[5];                                 // fc1 rows 5l..5l+4
#pragma unroll
  for (int j = 0; j < 5; ++j) h1[j] = 0.f;
  const float* swl = sw + 5 * l * 784;

  for (int wi = 0; wi < 14; ++wi) {
    const int r0 = 2 * wi;
    const bool hFull = (wi != 13);             // valid rows: 4 or 2
    float P[4][4];
#pragma unroll
    for (int r = 0; r < 4; ++r) {
      if (r < (hFull ? 4 : 2)) {
        float4 v = *(const float4*)(img + (r0 + r) * 28);
        P[r][0]=v.x; P[r][1]=v.y; P[r][2]=v.z; P[r][3]=v.w;
      } else {
        P[r][0]=0.f; P[r][1]=0.f; P[r][2]=0.f; P[r][3]=0.f;
      }
    }

    for (int wj = 0; wj < 14; ++wj) {
      if (wj > 0) {
#pragma unroll
        for (int r = 0; r < 4; ++r) { P[r][0] = P[r][2]; P[r][1] = P[r][3]; }
        const int c0 = 2 * wj + 2;
        if (c0 < 28) {
#pragma unroll
          for (int r = 0; r < 4; ++r) {
            if (r < (hFull ? 4 : 2)) {
              float2 v = *(const float2*)(img + (r0 + r) * 28 + c0);
              P[r][2] = v.x; P[r][3] = v.y;
            } else { P[r][2] = 0.f; P[r][3] = 0.f; }
          }
        } else {
#pragma unroll
          for (int r = 0; r < 4; ++r) { P[r][2] = 0.f; P[r][3] = 0.f; }
        }
      }
      const bool wFull = (wj != 13);

      // ---- per-lane angle pick: lane l gets packed f[5l .. 5l+4] ----
      float a0=0.f, a1=0.f, a2=0.f, a3=0.f, a4=0.f;
      if (hFull && wFull) {                    // f[k] = P[k>>2][k&3]
        if      (l == 0) { a0=P[0][0]; a1=P[0][1]; a2=P[0][2]; a3=P[0][3]; a4=P[1][0]; }
        else if (l == 1) { a0=P[1][1]; a1=P[1][2]; a2=P[1][3]; a3=P[2][0]; a4=P[2][1]; }
        else if (l == 2) { a0=P[2][2]; a1=P[2][3]; a2=P[3][0]; a3=P[3][1]; a4=P[3][2]; }
        else             { a0=P[3][3]; }
      } else if (hFull) {                      // w=2: f = P00,P01,P10,P11,P20,P21,P30,P31
        if      (l == 0) { a0=P[0][0]; a1=P[0][1]; a2=P[1][0]; a3=P[1][1]; a4=P[2][0]; }
        else if (l == 1) { a0=P[2][1]; a1=P[3][0]; a2=P[3][1]; }
      } else if (wFull) {                      // h=2: f = P00..P03,P10..P13
        if      (l == 0) { a0=P[0][0]; a1=P[0][1]; a2=P[0][2]; a3=P[0][3]; a4=P[1][0]; }
        else if (l == 1) { a0=P[1][1]; a1=P[1][2]; a2=P[1][3]; }
      } else {                                 // h=2,w=2: f = P00,P01,P10,P11
        if      (l == 0) { a0=P[0][0]; a1=P[0][1]; a2=P[1][0]; a3=P[1][1]; }
      }

      // ---- lane l builds U for wire l: RZ(a4)RY(a3)RZ(a2)RY(a1)RZ(a0)·H ----
      U2 u = {RS2,0.f, RS2,0.f, RS2,0.f, -RS2,0.f};
      u_rz(u, a0); u_ry(u, a1); u_rz(u, a2); u_ry(u, a3); u_rz(u, a4);

      // ---- wire 0 (partner lane^2, row bit = l>>1) ----
      {
        float b00r=dppf<QP_BC0>(u.r00), b00i=dppf<QP_BC0>(u.i00);
        float b01r=dppf<QP_BC0>(u.r01), b01i=dppf<QP_BC0>(u.i01);
        float b10r=dppf<QP_BC0>(u.r10), b10i=dppf<QP_BC0>(u.i10);
        float b11r=dppf<QP_BC0>(u.r11), b11i=dppf<QP_BC0>(u.i11);
        const bool hi = (l & 2);
        float uar = hi ? b11r : b00r, uai = hi ? b11i : b00i;
        float ubr = hi ? b10r : b01r, ubi = hi ? b10i : b01i;
#pragma unroll
        for (int k = 0; k < 4; ++k) {
          float pr = dppf<QP_XOR2>(sr[k]), pi = dppf<QP_XOR2>(si[k]);
          float ar = sr[k], ai = si[k];
          sr[k] = uar*ar - uai*ai + ubr*pr - ubi*pi;
          si[k] = uar*ai + uai*ar + ubr*pi + ubi*pr;
        }
      }
      // ---- wire 1 (partner lane^1, row bit = l&1) ----
      {
        float b00r=dppf<QP_BC1>(u.r00), b00i=dppf<QP_BC1>(u.i00);
        float b01r=dppf<QP_BC1>(u.r01), b01i=dppf<QP_BC1>(u.i01);
        float b10r=dppf<QP_BC1>(u.r10), b10i=dppf<QP_BC1>(u.i10);
        float b11r=dppf<QP_BC1>(u.r11), b11i=dppf<QP_BC1>(u.i11);
        const bool hi = (l & 1);
        float uar = hi ? b11r : b00r, uai = hi ? b11i : b00i;
        float ubr = hi ? b10r : b01r, ubi = hi ? b10i : b01i;
#pragma unroll
        for (int k = 0; k < 4; ++k) {
          float pr = dppf<QP_XOR1>(sr[k]), pi = dppf<QP_XOR1>(si[k]);
          float ar = sr[k], ai = si[k];
          sr[k] = uar*ar - uai*ai + ubr*pr - ubi*pi;
          si[k] = uar*ai + uai*ar + ubr*pi + ubi*pr;
        }
      }
      // ---- wire 2 (local pairs (k, k+2)) ----
      {
        float c00r=dppf<QP_BC2>(u.r00), c00i=dppf<QP_BC2>(u.i00);
        float c01r=dppf<QP_BC2>(u.r01), c01i=dppf<QP_BC2>(u.i01);
        float c10r=dppf<QP_BC2>(u.r10), c10i=dppf<QP_BC2>(u.i10);
        float c11r=dppf<QP_BC2>(u.r11), c11i=dppf<QP_BC2>(u.i11);
#pragma unroll
        for (int k = 0; k < 2; ++k) {
          float ar=sr[k], ai=si[k], br=sr[k+2], bi=si[k+2];
          sr[k]   = c00r*ar - c00i*ai + c01r*br - c01i*bi;
          si[k]   = c00r*ai + c00i*ar + c01r*bi + c01i*br;
          sr[k+2] = c10r*ar - c10i*ai + c11r*br - c11i*bi;
          si[k+2] = c10r*ai + c10i*ar + c11r*bi + c11i*br;
        }
      }
      // ---- wire 3 (local pairs (k, k+1)) ----
      {
        float c00r=dppf<QP_BC3>(u.r00), c00i=dppf<QP_BC3>(u.i00);
        float c01r=dppf<QP_BC3>(u.r01), c01i=dppf<QP_BC3>(u.i01);
        float c10r=dppf<QP_BC3>(u.r10), c10i=dppf<QP_BC3>(u.i10);
        float c11r=dppf<QP_BC3>(u.r11), c11i=dppf<QP_BC3>(u.i11);
#pragma unroll
        for (int k = 0; k < 4; k += 2) {
          float ar=sr[k], ai=si[k], br=sr[k+1], bi=si[k+1];
          sr[k]   = c00r*ar - c00i*ai + c01r*br - c01i*bi;
          si[k]   = c00r*ai + c00i*ar + c01r*bi + c01i*br;
          sr[k+1] = c10r*ar - c10i*ai + c11r*br - c11i*bi;
          si[k+1] = c10r*ai + c10i*ar + c11r*bi + c11i*br;
        }
      }

      // ---- CRZ ring diagonal (per-lane precomputed) ----
#pragma unroll
      for (int k = 0; k < 4; ++k) {
        float r = sr[k], im = si[k];
        sr[k] = czk[k]*r - szk[k]*im;
        si[k] = czk[k]*im + szk[k]*r;
      }

      // ---- Ry(ryt) on wires 0,1 (cross-lane) ----
#pragma unroll
      for (int k = 0; k < 4; ++k) {
        float pr = dppf<QP_XOR2>(sr[k]), pi = dppf<QP_XOR2>(si[k]);
        sr[k] = cry*sr[k] + sgn0*pr;
        si[k] = cry*si[k] + sgn0*pi;
      }
#pragma unroll
      for (int k = 0; k < 4; ++k) {
        float pr = dppf<QP_XOR1>(sr[k]), pi = dppf<QP_XOR1>(si[k]);
        sr[k] = cry*sr[k] + sgn1*pr;
        si[k] = cry*si[k] + sgn1*pi;
      }
      // ---- Ry on wires 2,3 (local) ----
#pragma unroll
      for (int k = 0; k < 2; ++k) {
        float ar=sr[k], br=sr[k+2];  sr[k]=cry*ar - sry*br;  sr[k+2]=sry*ar + cry*br;
        float ai=si[k], bi=si[k+2];  si[k]=cry*ai - sry*bi;  si[k+2]=sry*ai + cry*bi;
      }
#pragma unroll
      for (int k = 0; k < 4; k += 2) {
        float ar=sr[k], br=sr[k+1];  sr[k]=cry*ar - sry*br;  sr[k+1]=sry*ar + cry*br;
        float ai=si[k], bi=si[k+1];  si[k]=cry*ai - sry*bi;  si[k+1]=sry*ai + cry*bi;
      }

      // ---- Z expectations: per-lane partials then 4-lane butterfly ----
      float p0 = sr[0]*sr[0] + si[0]*si[0];
      float p1 = sr[1]*sr[1] + si[1]*si[1];
      float p2 = sr[2]*sr[2] + si[2]*si[2];
      float p3 = sr[3]*sr[3] + si[3]*si[3];
      float s01 = p0 + p1, s23 = p2 + p3;
      float t   = s01 + s23;
      float o0 = (l & 2) ? -t : t;          // sign = bit b0 = l>>1
      float o1 = (l & 1) ? -t : t;          // sign = bit b1 = l&1
      float o2 = s01 - s23;                 // sign = bit b2 = k>>1
      float o3 = (p0 - p1) + (p2 - p3);     // sign = bit b3 = k&1
      o0 += dppf<QP_XOR1>(o0); o0 += dppf<QP_XOR2>(o0);
      o1 += dppf<QP_XOR1>(o1); o1 += dppf<QP_XOR2>(o1);
      o2 += dppf<QP_XOR1>(o2); o2 += dppf<QP_XOR2>(o2);
      o3 += dppf<QP_XOR1>(o3); o3 += dppf<QP_XOR2>(o3);

      // ---- fc1 partial: this lane's 5 rows ----
      const int win4 = (wi * 14 + wj) * 4;
#pragma unroll
      for (int j = 0; j < 5; ++j) {
        float4 wv = *(const float4*)(swl + j * 784 + win4);
        h1[j] = fmaf(wv.x, o0, fmaf(wv.y, o1, fmaf(wv.z, o2, fmaf(wv.w, o3, h1[j]))));
      }
    }
  }

  // ---- epilogue: bias + leaky relu + fc2, reduce over group ----
  float pa = 0.f, pb = 0.f;
#pragma unroll
  for (int j = 0; j < 5; ++j) {
    const int r = 5 * l + j;
    float v = h1[j] + fc1_b[r];
    v = (v > 0.f) ? v : 0.1f * v;
    pa = fmaf(fc2_w[r],      v, pa);
    pb = fmaf(fc2_w[20 + r], v, pb);
  }
  pa += dppf<QP_XOR1>(pa); pa += dppf<QP_XOR2>(pa);
  pb += dppf<QP_XOR1>(pb); pb += dppf<QP_XOR2>(pb);
  if (l == 0) {
    float2 res; res.x = pa + fc2_b[0]; res.y = pb + fc2_b[1];
    *(float2*)(out + (size_t)b * 2) = res;
  }
}

extern "C" void kernel_launch(void* const* d_in, const int* in_sizes, int n_in,
                              void* d_out, int out_size, void* d_ws, size_t ws_size,
                              hipStream_t stream) {
  const float* x      = (const float*)d_in[0];
  const float* crz_t  = (const float*)d_in[1];
  const float* ry_t   = (const float*)d_in[2];
  const float* fc1_w  = (const float*)d_in[3];
  const float* fc1_b  = (const float*)d_in[4];
  const float* fc2_w  = (const float*)d_in[5];
  const float* fc2_b  = (const float*)d_in[6];
  float* out = (float*)d_out;
  const int B = in_sizes[0] / 784;
  const int grid = (B * 4 + 255) / 256;
  quanv_kernel<<<grid, 256, 0, stream>>>(x, crz_t, ry_t, fc1_w, fc1_b,
                                         fc2_w, fc2_b, out, B);
}